// Round 1
// baseline (404.305 us; speedup 1.0000x reference)
//
#include <hip/hip_runtime.h>
#include <hip/hip_fp16.h>

typedef unsigned short u16;
using f32x4 = __attribute__((ext_vector_type(4))) float;
using half8 = __attribute__((ext_vector_type(8))) _Float16;

#define N_PTS 8192
#define D_DIM 768
#define TOPK  21
#define N_STRIPES 8          // 8192 cols / 8 = 1024 cols per stripe
#define CT_PER_STRIPE 8      // 1024 / 128
#define KSTEPS 12            // 768 / 64

// ---------------- async global->LDS (16B per lane) ----------------
__device__ __forceinline__ void gload16(const void* g, void* l) {
    __builtin_amdgcn_global_load_lds(
        (const __attribute__((address_space(1))) void*)g,
        (__attribute__((address_space(3))) void*)l,
        16, 0, 0);
}

// ---------------- branch-free sorted top-k insert (ascending) ------
// t[] sorted ascending, t[TOPK-1] is current threshold.
__device__ __forceinline__ void topk_insert(float (&t)[TOPK], float x) {
    if (x >= t[TOPK - 1]) return;
#pragma unroll
    for (int i = TOPK - 1; i >= 1; --i) {
        float tp = t[i - 1];
        t[i] = (x < tp) ? tp : fminf(x, t[i]);
    }
    t[0] = fminf(t[0], x);
}

// ---------------- kernel 1: fp32 -> fp16 + row norms ----------------
__global__ __launch_bounds__(256) void prep_kernel(const float* __restrict__ X,
                                                   u16* __restrict__ Xh,
                                                   float* __restrict__ norms) {
    const int row = blockIdx.x;
    const int tid = threadIdx.x;
    const float* xr = X + (size_t)row * D_DIM;
    u16* hr = Xh + (size_t)row * D_DIM;
    float s = 0.f;
#pragma unroll
    for (int i = 0; i < 3; ++i) {
        float v = xr[tid + i * 256];
        _Float16 h = (_Float16)v;          // RNE fptrunc
        u16 hb;
        __builtin_memcpy(&hb, &h, 2);
        hr[tid + i * 256] = hb;
        float vb = (float)h;
        s += vb * vb;
    }
#pragma unroll
    for (int o = 32; o >= 1; o >>= 1) s += __shfl_down(s, o, 64);
    __shared__ float red[4];
    if ((tid & 63) == 0) red[tid >> 6] = s;
    __syncthreads();
    if (tid == 0) norms[row] = red[0] + red[1] + red[2] + red[3];
}

// ---------------- kernel 2: fused GEMM (S = Xh Xh^T) + per-row top-21 ----
// grid = 64 rowTiles * 8 stripes = 512 blocks, 256 threads (4 waves, 2x2).
__global__ __launch_bounds__(256) void gemm_topk_kernel(const u16* __restrict__ Xh,
                                                        const float* __restrict__ norms,
                                                        float* __restrict__ partials) {
    __shared__ __align__(16) u16 As[128 * 64];
    __shared__ __align__(16) u16 Bs[128 * 64];
    __shared__ float Ss[128 * 65];   // half-tile of r2 (64 cols + pad)
    __shared__ float nAs[128];
    __shared__ float nBs[128];

    const int tid  = threadIdx.x;
    const int lane = tid & 63;
    const int wid  = tid >> 6;
    const int wr   = wid >> 1;       // wave row (0..1) -> 64 rows
    const int wc   = wid & 1;        // wave col (0..1) -> 64 cols
    const int l16  = lane >> 4;
    const int l15  = lane & 15;

    const int bid     = blockIdx.x;
    const int rowTile = bid >> 3;
    const int stripe  = bid & 7;
    const int r0 = rowTile * 128;
    const int c0 = stripe * 1024;

    float t[TOPK];
#pragma unroll
    for (int i = 0; i < TOPK; ++i) t[i] = 3e38f;

    if (tid < 128) nAs[tid] = norms[r0 + tid];

    const int rb   = tid >> 3;        // 0..31 (+32*i)
    const int cole = (tid & 7) * 8;   // element col offset within 64-wide chunk
    const int lofs = tid * 8;         // u16 elems => tid*16 bytes

    for (int ct = 0; ct < CT_PER_STRIPE; ++ct) {
        const int cb = c0 + ct * 128;
        if (tid < 128) nBs[tid] = norms[cb + tid];

        f32x4 acc[4][4];
#pragma unroll
        for (int m = 0; m < 4; ++m)
#pragma unroll
            for (int n = 0; n < 4; ++n) {
                f32x4 z = {0.f, 0.f, 0.f, 0.f};
                acc[m][n] = z;
            }

        for (int ks = 0; ks < KSTEPS; ++ks) {
            const int kofs = ks * 64;
#pragma unroll
            for (int i = 0; i < 4; ++i) {
                const int r = i * 32 + rb;
                gload16(Xh + (size_t)(r0 + r) * D_DIM + kofs + cole, &As[i * 2048 + lofs]);
            }
#pragma unroll
            for (int i = 0; i < 4; ++i) {
                const int r = i * 32 + rb;
                gload16(Xh + (size_t)(cb + r) * D_DIM + kofs + cole, &Bs[i * 2048 + lofs]);
            }
            __syncthreads();
#pragma unroll
            for (int kk = 0; kk < 2; ++kk) {
                const int ko = kk * 32 + l16 * 8;
                half8 af[4], bf[4];
#pragma unroll
                for (int m = 0; m < 4; ++m)
                    af[m] = *reinterpret_cast<const half8*>(&As[(wr * 64 + m * 16 + l15) * 64 + ko]);
#pragma unroll
                for (int n = 0; n < 4; ++n)
                    bf[n] = *reinterpret_cast<const half8*>(&Bs[(wc * 64 + n * 16 + l15) * 64 + ko]);
#pragma unroll
                for (int m = 0; m < 4; ++m)
#pragma unroll
                    for (int n = 0; n < 4; ++n)
                        acc[m][n] = __builtin_amdgcn_mfma_f32_16x16x32_f16(af[m], bf[n], acc[m][n], 0, 0, 0);
            }
            __syncthreads();
        }

        // epilogue: two 128x64 halves -> r2 in LDS -> per-lane top-21
#pragma unroll
        for (int h = 0; h < 2; ++h) {
            if (wc == h) {
#pragma unroll
                for (int m = 0; m < 4; ++m)
#pragma unroll
                    for (int n = 0; n < 4; ++n)
#pragma unroll
                        for (int r = 0; r < 4; ++r) {
                            const int ri = wr * 64 + m * 16 + l16 * 4 + r;
                            const int ci = n * 16 + l15;
                            Ss[ri * 65 + ci] = nAs[ri] + nBs[h * 64 + ci] - 2.0f * acc[m][n][r];
                        }
            }
            __syncthreads();
            {
                const int srow = tid >> 1;
                const int sc0  = (tid & 1) * 32;
                const float* sr = &Ss[srow * 65 + sc0];
                for (int j = 0; j < 32; ++j) topk_insert(t, sr[j]);
            }
            __syncthreads();
        }
    }

    // merge lane pairs (even lane keeps union top-21 of its row)
#pragma unroll
    for (int i = 0; i < TOPK; ++i) {
        float pv = __shfl_xor(t[i], 1, 64);
        if ((tid & 1) == 0) topk_insert(t, pv);
    }
    if ((tid & 1) == 0) {
        const int row = r0 + (tid >> 1);
        float* dst = partials + ((size_t)row * N_STRIPES + stripe) * TOPK;
#pragma unroll
        for (int i = 0; i < TOPK; ++i) dst[i] = t[i];
    }
}

// ---------------- kernel 3: merge stripes + LID math ----------------
__global__ __launch_bounds__(256) void finalize_kernel(const float* __restrict__ partials,
                                                       float* __restrict__ out) {
    const int row = blockIdx.x * 256 + threadIdx.x;
    if (row >= N_PTS) return;
    const float* p = partials + (size_t)row * (N_STRIPES * TOPK);
    float t[TOPK];
#pragma unroll
    for (int i = 0; i < TOPK; ++i) t[i] = 3e38f;
    for (int i = 0; i < N_STRIPES * TOPK; ++i) topk_insert(t, p[i]);

    float S = 0.f, amin = 3e38f, amax = -3e38f;
#pragma unroll
    for (int i = 0; i < TOPK; ++i) {
        float a = sqrtf(fmaxf(t[i], 1e-12f));
        S += a;
        amin = fminf(amin, a);
        amax = fmaxf(amax, a);
    }
    // a0 = amin (self), a20 = amax; m = mean of the middle 19
    float m = (S - amin - amax) * (1.0f / 19.0f);
    float lid = m / (amax - m);
    out[row] = -fabsf(logf(lid));
}

extern "C" void kernel_launch(void* const* d_in, const int* in_sizes, int n_in,
                              void* d_out, int out_size, void* d_ws, size_t ws_size,
                              hipStream_t stream) {
    const float* X = (const float*)d_in[0];
    float* out = (float*)d_out;
    char* ws = (char*)d_ws;

    u16* Xh        = (u16*)ws;                        // 8192*768*2   = 12,582,912 B
    float* norms   = (float*)(ws + 12582912);         // 8192*4       =     32,768 B
    float* partials= (float*)(ws + 12615680);         // 8192*8*21*4  =  5,505,024 B

    prep_kernel<<<N_PTS, 256, 0, stream>>>(X, Xh, norms);
    gemm_topk_kernel<<<64 * N_STRIPES, 256, 0, stream>>>(Xh, norms, partials);
    finalize_kernel<<<N_PTS / 256, 256, 0, stream>>>(partials, out);
}